// Round 4
// baseline (233.561 us; speedup 1.0000x reference)
//
#include <hip/hip_runtime.h>
#include <hip/hip_bf16.h>

// Problem constants: B=2, S=2048, H=16, dk=64, D_MODEL=1024, THETA=10000

using u16 = unsigned short;
typedef __attribute__((ext_vector_type(8))) short short8;
typedef __attribute__((ext_vector_type(4))) float f32x4;
typedef __attribute__((ext_vector_type(16))) float f32x16;
typedef __attribute__((ext_vector_type(2))) unsigned uint2v;
typedef __attribute__((ext_vector_type(4))) unsigned uint4v;

__device__ __forceinline__ float bf2f(u16 v) {
  unsigned u = ((unsigned)v) << 16; float f; __builtin_memcpy(&f, &u, 4); return f;
}
__device__ __forceinline__ u16 f2bf(float f) {
  unsigned u; __builtin_memcpy(&u, &f, 4);
  return (u16)((u + 0x7fffu + ((u >> 16) & 1u)) >> 16);
}

__device__ __forceinline__ void gload_lds16(const void* g, void* l) {
  __builtin_amdgcn_global_load_lds((const __attribute__((address_space(1))) unsigned*)g,
                                   (__attribute__((address_space(3))) unsigned*)l, 16, 0, 0);
}

// ---------------- fused fp32 -> bf16 convert for x, W_qkv, W_o ----------------
__global__ __launch_bounds__(256) void cvt_all(const float* __restrict__ x, const float* __restrict__ wqkv,
                                               const float* __restrict__ wo, u16* __restrict__ xb,
                                               u16* __restrict__ wqkvb, u16* __restrict__ wob) {
  int i = blockIdx.x * 256 + threadIdx.x;  // 2M quads total
  const float* src; u16* dst; int off;
  if (i < 1048576) { src = x; dst = xb; off = i; }
  else if (i < 1048576 + 786432) { src = wqkv; dst = wqkvb; off = i - 1048576; }
  else { src = wo; dst = wob; off = i - (1048576 + 786432); }
  float4 v = *(const float4*)(src + (size_t)off * 4);
  unsigned lo = f2bf(v.x) | ((unsigned)f2bf(v.y) << 16);
  unsigned hi = f2bf(v.z) | ((unsigned)f2bf(v.w) << 16);
  uint2 w; w.x = lo; w.y = hi;
  *(uint2*)(dst + (size_t)off * 4) = w;
}

// ---------------- GEMM: C[M,N] = A[M,K] * B[N,K]^T, bf16 in, fp32 acc ----------------
template <typename OutT>
__global__ __launch_bounds__(256) void gemm_bt(const u16* __restrict__ A, const u16* __restrict__ B,
                                               OutT* __restrict__ C, int M, int N, int K) {
  __shared__ u16 As[128 * 32];
  __shared__ u16 Bs[128 * 32];
  const int tid = threadIdx.x;
  const int wave = tid >> 6;
  const int lane = tid & 63;
  const int m0 = blockIdx.x * 128;
  const int n0 = blockIdx.y * 128;
  const int wm = (wave >> 1) * 64;
  const int wn = (wave & 1) * 64;

  f32x4 acc[4][4];
#pragma unroll
  for (int m = 0; m < 4; ++m)
#pragma unroll
    for (int n = 0; n < 4; ++n) acc[m][n] = (f32x4){0.f, 0.f, 0.f, 0.f};

  const int srow = lane >> 2;
  const int scol = (lane & 3) * 8;
  const u16* Ag0 = A + (size_t)(m0 + wave * 16 + srow) * K + scol;
  const u16* Ag1 = A + (size_t)(m0 + 64 + wave * 16 + srow) * K + scol;
  const u16* Bg0 = B + (size_t)(n0 + wave * 16 + srow) * K + scol;
  const u16* Bg1 = B + (size_t)(n0 + 64 + wave * 16 + srow) * K + scol;
  u16* AsW0 = As + (wave * 16) * 32;
  u16* AsW1 = As + (64 + wave * 16) * 32;
  u16* BsW0 = Bs + (wave * 16) * 32;
  u16* BsW1 = Bs + (64 + wave * 16) * 32;

  const int fr = lane & 15;
  const int fk = (lane >> 4) * 8;

  for (int k0 = 0; k0 < K; k0 += 32) {
    __syncthreads();
    gload_lds16(Ag0 + k0, AsW0);
    gload_lds16(Ag1 + k0, AsW1);
    gload_lds16(Bg0 + k0, BsW0);
    gload_lds16(Bg1 + k0, BsW1);
    __syncthreads();

    short8 af[4], bf[4];
#pragma unroll
    for (int m = 0; m < 4; ++m)
      af[m] = *(const short8*)(As + (wm + m * 16 + fr) * 32 + fk);
#pragma unroll
    for (int n = 0; n < 4; ++n)
      bf[n] = *(const short8*)(Bs + (wn + n * 16 + fr) * 32 + fk);
#pragma unroll
    for (int m = 0; m < 4; ++m)
#pragma unroll
      for (int n = 0; n < 4; ++n)
        acc[m][n] = __builtin_amdgcn_mfma_f32_16x16x32_bf16(af[m], bf[n], acc[m][n], 0, 0, 0);
  }

  const int fg = lane >> 4;
#pragma unroll
  for (int m = 0; m < 4; ++m)
#pragma unroll
    for (int n = 0; n < 4; ++n)
#pragma unroll
      for (int r = 0; r < 4; ++r) {
        int row = m0 + wm + m * 16 + fg * 4 + r;
        int col = n0 + wn + n * 16 + fr;
        if constexpr (sizeof(OutT) == 2)
          C[(size_t)row * N + col] = (OutT)f2bf(acc[m][n][r]);
        else
          C[(size_t)row * N + col] = (OutT)acc[m][n][r];
      }
}

// ---------------- RoPE on Q,K: qkv[B,S,3072] -> Qr,Kr [B,H,S,64] ----------------
// Q pre-scaled by (1/sqrt(dk)) * log2(e) = 0.125 * 1.4426950 so QK^T scores land
// in log2 domain: softmax exp becomes a bare v_exp_f32 (2^x).
__global__ __launch_bounds__(256) void rope_qk(const u16* __restrict__ qkv, const int* __restrict__ pos,
                                               u16* __restrict__ Qr, u16* __restrict__ Kr) {
  int t = blockIdx.x * 256 + threadIdx.x;
  int i = t & 31;
  int h = (t >> 5) & 15;
  int s = (t >> 9) & 2047;
  int b = t >> 20;
  float p = (float)pos[(b << 11) + s];
  float ang = p * __builtin_exp2f(-(float)i * 0.41524101186f);
  float sn, cs;
  sincosf(ang, &sn, &cs);
  const u16* base = qkv + ((size_t)((b << 11) + s)) * 3072 + h * 64 + 2 * i;
  float qe = bf2f(base[0]), qo = bf2f(base[1]);
  float ke = bf2f(base[1024]), ko = bf2f(base[1025]);
  size_t o = (((size_t)((b << 4) + h) << 11) + s) * 64 + 2 * i;
  const float QS = 0.18033688011112043f;  // 0.125 * log2(e)
  unsigned qw = f2bf((cs * qe - sn * qo) * QS) | ((unsigned)f2bf((sn * qe + cs * qo) * QS) << 16);
  unsigned kw = f2bf(cs * ke - sn * ko) | ((unsigned)f2bf(sn * ke + cs * ko) << 16);
  *(unsigned*)(Qr + o) = qw;
  *(unsigned*)(Kr + o) = kw;
}

// ---------------- V transpose: qkv V-part -> Vt [B,H,64,S] ----------------
__global__ __launch_bounds__(256) void v_transpose(const u16* __restrict__ qkv, u16* __restrict__ Vt) {
  __shared__ u16 tile[256][64];
  const int bh = blockIdx.y;
  const int b = bh >> 4, h = bh & 15;
  const int s0 = blockIdx.x * 256;
  const int tid = threadIdx.x;
  {
    const int c = tid & 7;
    const int r = tid >> 3;
#pragma unroll
    for (int p = 0; p < 8; ++p) {
      int s = r + p * 32;
      const u16* src = qkv + ((size_t)((b << 11) + s0 + s)) * 3072 + 2048 + h * 64 + c * 8;
      *(uint4*)&tile[s][c * 8] = *(const uint4*)src;
    }
  }
  __syncthreads();
  {
    const int c = tid & 31;
    const int r = tid >> 5;
#pragma unroll
    for (int p = 0; p < 8; ++p) {
      int d = r + p * 8;
      u16 tmp[8];
#pragma unroll
      for (int j = 0; j < 8; ++j) tmp[j] = tile[c * 8 + j][d];
      u16* dst = Vt + ((size_t)bh * 64 + d) * 2048 + s0 + c * 8;
      *(uint4*)dst = *(uint4*)tmp;
    }
  }
}

// ---------------- causal flash attention v4 ----------------
// Same structure as v3 (2 waves/block, 2-way key-split per 32-row q-tile,
// swapped QK^T 32x32x16, in-register log2-domain softmax, defer-max,
// cvt_pk+permlane32_swap P). Fixes round-3's accumulator SPILL:
// __launch_bounds__(128,2) -> 256-VGPR budget; V frags loaded after QK^T.
__global__ __launch_bounds__(128, 2) void attn4(const u16* __restrict__ Qr, const u16* __restrict__ Kr,
                                                const u16* __restrict__ Vt, u16* __restrict__ Ao) {
  __shared__ float smM[64], smL[64];
  __shared__ float smO[64][33];
  const int tid = threadIdx.x;
  const int lane = tid & 63;
  const int wid = tid >> 6;
  const int bid = blockIdx.x;            // 2048 = 8 xcd * 4 bh * 64 qt
  const int xcd = bid & 7;
  const int rr = bid >> 3;
  const int bh = xcd * 4 + (rr & 3);     // 4 bh per XCD -> K/V 2MB, L2-fits
  const int qt = 63 - (rr >> 2);         // heavy q-tiles dispatched first
  const int q0 = qt * 32;
  const u16* __restrict__ Qp = Qr + ((size_t)bh << 11) * 64;
  const u16* __restrict__ Kp = Kr + ((size_t)bh << 11) * 64;
  const u16* __restrict__ Vp = Vt + ((size_t)bh << 11) * 64;  // [64][2048]
  const int lq = lane & 31;
  const int hi = lane >> 5;

  short8 qf0 = *(const short8*)(Qp + (size_t)(q0 + lq) * 64 + 0 + hi * 8);
  short8 qf1 = *(const short8*)(Qp + (size_t)(q0 + lq) * 64 + 16 + hi * 8);
  short8 qf2 = *(const short8*)(Qp + (size_t)(q0 + lq) * 64 + 32 + hi * 8);
  short8 qf3 = *(const short8*)(Qp + (size_t)(q0 + lq) * 64 + 48 + hi * 8);

  f32x16 o0, o1;
#pragma unroll
  for (int r = 0; r < 16; ++r) { o0[r] = 0.f; o1[r] = 0.f; }
  float m = -1e30f, lsum = 0.f;

  const int nkt = qt + 1;
  const int half = (nkt + 1) >> 1;
  const int ktbeg = wid ? half : 0;
  const int ktend = wid ? nkt : half;

  for (int kt = ktbeg; kt < ktend; ++kt) {
    const int kb = kt << 5;
    const u16* kp = Kp + (size_t)(kb + lq) * 64 + hi * 8;
    short8 kf0 = *(const short8*)(kp);
    short8 kf1 = *(const short8*)(kp + 16);
    short8 kf2 = *(const short8*)(kp + 32);
    short8 kf3 = *(const short8*)(kp + 48);

    f32x16 sc;
#pragma unroll
    for (int r = 0; r < 16; ++r) sc[r] = 0.f;
    sc = __builtin_amdgcn_mfma_f32_32x32x16_bf16(kf0, qf0, sc, 0, 0, 0);
    sc = __builtin_amdgcn_mfma_f32_32x32x16_bf16(kf1, qf1, sc, 0, 0, 0);
    sc = __builtin_amdgcn_mfma_f32_32x32x16_bf16(kf2, qf2, sc, 0, 0, 0);
    sc = __builtin_amdgcn_mfma_f32_32x32x16_bf16(kf3, qf3, sc, 0, 0, 0);

    // V frags AFTER QK^T: kf regs die above, keeping peak pressure < budget.
    const u16* vp = Vp + (size_t)lq * 2048 + kb + hi * 8;
    short8 vf00 = *(const short8*)(vp);
    short8 vf01 = *(const short8*)(vp + 16);
    short8 vf10 = *(const short8*)(vp + (size_t)32 * 2048);
    short8 vf11 = *(const short8*)(vp + (size_t)32 * 2048 + 16);

    if (kt == qt) {  // diagonal tile: causal mask
#pragma unroll
      for (int r = 0; r < 16; ++r) {
        int ko = (r & 3) + 8 * (r >> 2) + 4 * hi;
        sc[r] = (ko <= lq) ? sc[r] : -1e30f;
      }
    }

    // row max via max3 nest (8 ops), then cross-half exchange
    float t0 = fmaxf(fmaxf(sc[0], sc[1]), sc[2]);
    float t1 = fmaxf(fmaxf(sc[3], sc[4]), sc[5]);
    float t2 = fmaxf(fmaxf(sc[6], sc[7]), sc[8]);
    float t3 = fmaxf(fmaxf(sc[9], sc[10]), sc[11]);
    float t4 = fmaxf(fmaxf(sc[12], sc[13]), sc[14]);
    float t5 = fmaxf(fmaxf(t0, t1), sc[15]);
    float t6 = fmaxf(fmaxf(t2, t3), t4);
    float pmax = fmaxf(t5, t6);
    pmax = fmaxf(pmax, __shfl_xor(pmax, 32));

    // defer-max (log2 domain, THR = 8 nats * log2e = 11.5)
    if (!__all(pmax - m <= 11.5f)) {
      float nm = fmaxf(m, pmax);
      float alpha = __builtin_exp2f(m - nm);
      lsum *= alpha;
#pragma unroll
      for (int r = 0; r < 16; ++r) { o0[r] *= alpha; o1[r] *= alpha; }
      m = nm;
    }

    // P = 2^(S - m), in place
#pragma unroll
    for (int r = 0; r < 16; ++r) sc[r] = __builtin_exp2f(sc[r] - m);
    float r8[8];
#pragma unroll
    for (int r = 0; r < 8; ++r) r8[r] = sc[r] + sc[r + 8];
#pragma unroll
    for (int s = 4; s >= 1; s >>= 1)
#pragma unroll
      for (int r = 0; r < s; ++r) r8[r] += r8[r + s];
    lsum += r8[0] + __shfl_xor(r8[0], 32);

    // P -> bf16 B-operand: cvt_pk pairs + permlane32_swap
    unsigned w[8];
#pragma unroll
    for (int t = 0; t < 8; ++t) {
      unsigned d;
      asm("v_cvt_pk_bf16_f32 %0, %1, %2" : "=v"(d) : "v"(sc[2 * t]), "v"(sc[2 * t + 1]));
      w[t] = d;
    }
    short8 pb0, pb1;
    {
      uint2v r1 = __builtin_amdgcn_permlane32_swap(w[0], w[2], false, false);
      uint2v r2 = __builtin_amdgcn_permlane32_swap(w[1], w[3], false, false);
      uint4v t4; t4.x = r1.x; t4.y = r2.x; t4.z = r1.y; t4.w = r2.y;
      pb0 = __builtin_bit_cast(short8, t4);
      uint2v r3 = __builtin_amdgcn_permlane32_swap(w[4], w[6], false, false);
      uint2v r4 = __builtin_amdgcn_permlane32_swap(w[5], w[7], false, false);
      uint4v t5v; t5v.x = r3.x; t5v.y = r4.x; t5v.z = r3.y; t5v.w = r4.y;
      pb1 = __builtin_bit_cast(short8, t5v);
    }

    o0 = __builtin_amdgcn_mfma_f32_32x32x16_bf16(vf00, pb0, o0, 0, 0, 0);
    o0 = __builtin_amdgcn_mfma_f32_32x32x16_bf16(vf01, pb1, o0, 0, 0, 0);
    o1 = __builtin_amdgcn_mfma_f32_32x32x16_bf16(vf10, pb0, o1, 0, 0, 0);
    o1 = __builtin_amdgcn_mfma_f32_32x32x16_bf16(vf11, pb1, o1, 0, 0, 0);
  }

  // merge the two waves' partials
  if (wid == 1) {
    smM[lane] = m;
    smL[lane] = lsum;
#pragma unroll
    for (int r = 0; r < 16; ++r) smO[lane][r] = o0[r];
#pragma unroll
    for (int r = 0; r < 16; ++r) smO[lane][16 + r] = o1[r];
  }
  __syncthreads();
  if (wid == 0) {
    float m1 = smM[lane], l1 = smL[lane];
    float M = fmaxf(m, m1);
    float a0 = __builtin_exp2f(m - M), a1 = __builtin_exp2f(m1 - M);
    float L = lsum * a0 + l1 * a1;
    float inv = 1.f / L;
    const int b = bh >> 4, h = bh & 15;
    u16* outp = Ao + ((size_t)(b << 11) + q0 + lq) * 1024 + h * 64;
#pragma unroll
    for (int g = 0; g < 4; ++g) {
      int d = 8 * g + 4 * hi;
      float c0 = (o0[4 * g + 0] * a0 + smO[lane][4 * g + 0] * a1) * inv;
      float c1 = (o0[4 * g + 1] * a0 + smO[lane][4 * g + 1] * a1) * inv;
      float c2 = (o0[4 * g + 2] * a0 + smO[lane][4 * g + 2] * a1) * inv;
      float c3 = (o0[4 * g + 3] * a0 + smO[lane][4 * g + 3] * a1) * inv;
      uint2v w0;
      w0.x = f2bf(c0) | ((unsigned)f2bf(c1) << 16);
      w0.y = f2bf(c2) | ((unsigned)f2bf(c3) << 16);
      *(uint2v*)(outp + d) = w0;
      float c4 = (o1[4 * g + 0] * a0 + smO[lane][16 + 4 * g + 0] * a1) * inv;
      float c5 = (o1[4 * g + 1] * a0 + smO[lane][16 + 4 * g + 1] * a1) * inv;
      float c6 = (o1[4 * g + 2] * a0 + smO[lane][16 + 4 * g + 2] * a1) * inv;
      float c7 = (o1[4 * g + 3] * a0 + smO[lane][16 + 4 * g + 3] * a1) * inv;
      uint2v w1;
      w1.x = f2bf(c4) | ((unsigned)f2bf(c5) << 16);
      w1.y = f2bf(c6) | ((unsigned)f2bf(c7) << 16);
      *(uint2v*)(outp + 32 + d) = w1;
    }
  }
}

extern "C" void kernel_launch(void* const* d_in, const int* in_sizes, int n_in,
                              void* d_out, int out_size, void* d_ws, size_t ws_size,
                              hipStream_t stream) {
  const float* x = (const float*)d_in[0];
  const int* pos = (const int*)d_in[1];
  const float* Wqkv = (const float*)d_in[2];
  const float* Wo = (const float*)d_in[3];
  float* out = (float*)d_out;

  char* ws = (char*)d_ws;
  const size_t MB = 1024 * 1024;
  u16* xb     = (u16*)(ws);             //  8 MB: [4096,1024]
  u16* wqkvb  = (u16*)(ws + 8 * MB);    //  6 MB: [3072,1024]
  u16* wob    = (u16*)(ws + 14 * MB);   //  2 MB: [1024,1024]
  u16* qkv    = (u16*)(ws + 16 * MB);   // 24 MB: [4096,3072]
  u16* Qr     = (u16*)(ws + 40 * MB);   //  8 MB: [B,H,S,64] (pre-scaled 0.125*log2e)
  u16* Kr     = (u16*)(ws + 48 * MB);   //  8 MB
  u16* Vt     = (u16*)(ws + 56 * MB);   //  8 MB: [B,H,64,S]
  u16* ao     = (u16*)(ws + 64 * MB);   //  8 MB: [4096,1024]

  cvt_all<<<8192, 256, 0, stream>>>(x, Wqkv, Wo, xb, wqkvb, wob);
  gemm_bt<u16><<<dim3(32, 24), 256, 0, stream>>>(xb, wqkvb, qkv, 4096, 3072, 1024);
  rope_qk<<<8192, 256, 0, stream>>>(qkv, pos, Qr, Kr);
  v_transpose<<<dim3(8, 32), 256, 0, stream>>>(qkv, Vt);
  attn4<<<2048, 128, 0, stream>>>(Qr, Kr, Vt, ao);
  gemm_bt<float><<<dim3(32, 8), 256, 0, stream>>>(ao, wob, out, 4096, 1024, 1024);
}

// Round 6
// 227.943 us; speedup vs baseline: 1.0246x; 1.0246x over previous
//
#include <hip/hip_runtime.h>
#include <hip/hip_bf16.h>

// Problem constants: B=2, S=2048, H=16, dk=64, D_MODEL=1024, THETA=10000

using u16 = unsigned short;
typedef __attribute__((ext_vector_type(8))) short short8;
typedef __attribute__((ext_vector_type(4))) float f32x4;
typedef __attribute__((ext_vector_type(16))) float f32x16;
typedef __attribute__((ext_vector_type(2))) unsigned uint2v;
typedef __attribute__((ext_vector_type(4))) unsigned uint4v;

__device__ __forceinline__ float bf2f(u16 v) {
  unsigned u = ((unsigned)v) << 16; float f; __builtin_memcpy(&f, &u, 4); return f;
}
__device__ __forceinline__ u16 f2bf(float f) {
  unsigned u; __builtin_memcpy(&u, &f, 4);
  return (u16)((u + 0x7fffu + ((u >> 16) & 1u)) >> 16);
}
__device__ __forceinline__ float u2f(unsigned u) {
  float f; __builtin_memcpy(&f, &u, 4); return f;
}
__device__ __forceinline__ unsigned f2u(float f) {
  unsigned u; __builtin_memcpy(&u, &f, 4); return u;
}
__device__ __forceinline__ float xhalf_max(float x) {  // max with lane^32, VALU-only
  uint2v s = __builtin_amdgcn_permlane32_swap(f2u(x), f2u(x), false, false);
  unsigned ax = s.x, bx = s.y;
  return fmaxf(u2f(ax), u2f(bx));
}
__device__ __forceinline__ float xhalf_sum(float x) {  // sum with lane^32, VALU-only
  uint2v s = __builtin_amdgcn_permlane32_swap(f2u(x), f2u(x), false, false);
  unsigned ax = s.x, bx = s.y;
  return u2f(ax) + u2f(bx);
}

__device__ __forceinline__ void gload_lds16(const void* g, void* l) {
  __builtin_amdgcn_global_load_lds((const __attribute__((address_space(1))) unsigned*)g,
                                   (__attribute__((address_space(3))) unsigned*)l, 16, 0, 0);
}

// ---------------- fused fp32 -> bf16 convert for x, W_qkv, W_o ----------------
__global__ __launch_bounds__(256) void cvt_all(const float* __restrict__ x, const float* __restrict__ wqkv,
                                               const float* __restrict__ wo, u16* __restrict__ xb,
                                               u16* __restrict__ wqkvb, u16* __restrict__ wob) {
  int i = blockIdx.x * 256 + threadIdx.x;  // 2M quads total
  const float* src; u16* dst; int off;
  if (i < 1048576) { src = x; dst = xb; off = i; }
  else if (i < 1048576 + 786432) { src = wqkv; dst = wqkvb; off = i - 1048576; }
  else { src = wo; dst = wob; off = i - (1048576 + 786432); }
  float4 v = *(const float4*)(src + (size_t)off * 4);
  unsigned lo = f2bf(v.x) | ((unsigned)f2bf(v.y) << 16);
  unsigned hi = f2bf(v.z) | ((unsigned)f2bf(v.w) << 16);
  uint2 w; w.x = lo; w.y = hi;
  *(uint2*)(dst + (size_t)off * 4) = w;
}

// ---------------- GEMM 128x128: C[M,N] = A[M,K] * B[N,K]^T ----------------
template <typename OutT>
__global__ __launch_bounds__(256) void gemm_bt(const u16* __restrict__ A, const u16* __restrict__ B,
                                               OutT* __restrict__ C, int M, int N, int K) {
  __shared__ u16 As[128 * 32];
  __shared__ u16 Bs[128 * 32];
  const int tid = threadIdx.x;
  const int wave = tid >> 6;
  const int lane = tid & 63;
  const int m0 = blockIdx.x * 128;
  const int n0 = blockIdx.y * 128;
  const int wm = (wave >> 1) * 64;
  const int wn = (wave & 1) * 64;

  f32x4 acc[4][4];
#pragma unroll
  for (int m = 0; m < 4; ++m)
#pragma unroll
    for (int n = 0; n < 4; ++n) acc[m][n] = (f32x4){0.f, 0.f, 0.f, 0.f};

  const int srow = lane >> 2;
  const int scol = (lane & 3) * 8;
  const u16* Ag0 = A + (size_t)(m0 + wave * 16 + srow) * K + scol;
  const u16* Ag1 = A + (size_t)(m0 + 64 + wave * 16 + srow) * K + scol;
  const u16* Bg0 = B + (size_t)(n0 + wave * 16 + srow) * K + scol;
  const u16* Bg1 = B + (size_t)(n0 + 64 + wave * 16 + srow) * K + scol;
  u16* AsW0 = As + (wave * 16) * 32;
  u16* AsW1 = As + (64 + wave * 16) * 32;
  u16* BsW0 = Bs + (wave * 16) * 32;
  u16* BsW1 = Bs + (64 + wave * 16) * 32;

  const int fr = lane & 15;
  const int fk = (lane >> 4) * 8;

  for (int k0 = 0; k0 < K; k0 += 32) {
    __syncthreads();
    gload_lds16(Ag0 + k0, AsW0);
    gload_lds16(Ag1 + k0, AsW1);
    gload_lds16(Bg0 + k0, BsW0);
    gload_lds16(Bg1 + k0, BsW1);
    __syncthreads();

    short8 af[4], bf[4];
#pragma unroll
    for (int m = 0; m < 4; ++m)
      af[m] = *(const short8*)(As + (wm + m * 16 + fr) * 32 + fk);
#pragma unroll
    for (int n = 0; n < 4; ++n)
      bf[n] = *(const short8*)(Bs + (wn + n * 16 + fr) * 32 + fk);
#pragma unroll
    for (int m = 0; m < 4; ++m)
#pragma unroll
      for (int n = 0; n < 4; ++n)
        acc[m][n] = __builtin_amdgcn_mfma_f32_16x16x32_bf16(af[m], bf[n], acc[m][n], 0, 0, 0);
  }

  const int fg = lane >> 4;
#pragma unroll
  for (int m = 0; m < 4; ++m)
#pragma unroll
    for (int n = 0; n < 4; ++n)
#pragma unroll
      for (int r = 0; r < 4; ++r) {
        int row = m0 + wm + m * 16 + fg * 4 + r;
        int col = n0 + wn + n * 16 + fr;
        if constexpr (sizeof(OutT) == 2)
          C[(size_t)row * N + col] = (OutT)f2bf(acc[m][n][r]);
        else
          C[(size_t)row * N + col] = (OutT)acc[m][n][r];
      }
}

// ---------------- GEMM 64x128 (occupancy variant for small-M outputs) ----------------
template <typename OutT>
__global__ __launch_bounds__(256) void gemm_bt64(const u16* __restrict__ A, const u16* __restrict__ B,
                                                 OutT* __restrict__ C, int M, int N, int K) {
  __shared__ u16 As[64 * 32];   // 4 KB
  __shared__ u16 Bs[128 * 32];  // 8 KB
  const int tid = threadIdx.x;
  const int wave = tid >> 6;
  const int lane = tid & 63;
  const int m0 = blockIdx.x * 64;
  const int n0 = blockIdx.y * 128;
  const int wm = (wave >> 1) * 32;
  const int wn = (wave & 1) * 64;

  f32x4 acc[2][4];
#pragma unroll
  for (int m = 0; m < 2; ++m)
#pragma unroll
    for (int n = 0; n < 4; ++n) acc[m][n] = (f32x4){0.f, 0.f, 0.f, 0.f};

  const int srow = lane >> 2;
  const int scol = (lane & 3) * 8;
  const u16* Ag = A + (size_t)(m0 + wave * 16 + srow) * K + scol;
  const u16* Bg0 = B + (size_t)(n0 + wave * 16 + srow) * K + scol;
  const u16* Bg1 = B + (size_t)(n0 + 64 + wave * 16 + srow) * K + scol;
  u16* AsW = As + (wave * 16) * 32;
  u16* BsW0 = Bs + (wave * 16) * 32;
  u16* BsW1 = Bs + (64 + wave * 16) * 32;

  const int fr = lane & 15;
  const int fk = (lane >> 4) * 8;

  for (int k0 = 0; k0 < K; k0 += 32) {
    __syncthreads();
    gload_lds16(Ag + k0, AsW);
    gload_lds16(Bg0 + k0, BsW0);
    gload_lds16(Bg1 + k0, BsW1);
    __syncthreads();

    short8 af[2], bf[4];
#pragma unroll
    for (int m = 0; m < 2; ++m)
      af[m] = *(const short8*)(As + (wm + m * 16 + fr) * 32 + fk);
#pragma unroll
    for (int n = 0; n < 4; ++n)
      bf[n] = *(const short8*)(Bs + (wn + n * 16 + fr) * 32 + fk);
#pragma unroll
    for (int m = 0; m < 2; ++m)
#pragma unroll
      for (int n = 0; n < 4; ++n)
        acc[m][n] = __builtin_amdgcn_mfma_f32_16x16x32_bf16(af[m], bf[n], acc[m][n], 0, 0, 0);
  }

  const int fg = lane >> 4;
#pragma unroll
  for (int m = 0; m < 2; ++m)
#pragma unroll
    for (int n = 0; n < 4; ++n)
#pragma unroll
      for (int r = 0; r < 4; ++r) {
        int row = m0 + wm + m * 16 + fg * 4 + r;
        int col = n0 + wn + n * 16 + fr;
        if constexpr (sizeof(OutT) == 2)
          C[(size_t)row * N + col] = (OutT)f2bf(acc[m][n][r]);
        else
          C[(size_t)row * N + col] = (OutT)acc[m][n][r];
      }
}

// ---------------- RoPE on Q,K -> Qr,Kr [B,H,S,64]; Q pre-scaled 0.125*log2(e) ----------------
__global__ __launch_bounds__(256) void rope_qk(const u16* __restrict__ qkv, const int* __restrict__ pos,
                                               u16* __restrict__ Qr, u16* __restrict__ Kr) {
  int t = blockIdx.x * 256 + threadIdx.x;
  int i = t & 31;
  int h = (t >> 5) & 15;
  int s = (t >> 9) & 2047;
  int b = t >> 20;
  float p = (float)pos[(b << 11) + s];
  float ang = p * __builtin_exp2f(-(float)i * 0.41524101186f);
  float sn, cs;
  sincosf(ang, &sn, &cs);
  const u16* base = qkv + ((size_t)((b << 11) + s)) * 3072 + h * 64 + 2 * i;
  float qe = bf2f(base[0]), qo = bf2f(base[1]);
  float ke = bf2f(base[1024]), ko = bf2f(base[1025]);
  size_t o = (((size_t)((b << 4) + h) << 11) + s) * 64 + 2 * i;
  const float QS = 0.18033688011112043f;  // 0.125 * log2(e)
  unsigned qw = f2bf((cs * qe - sn * qo) * QS) | ((unsigned)f2bf((sn * qe + cs * qo) * QS) << 16);
  unsigned kw = f2bf(cs * ke - sn * ko) | ((unsigned)f2bf(sn * ke + cs * ko) << 16);
  *(unsigned*)(Qr + o) = qw;
  *(unsigned*)(Kr + o) = kw;
}

// ---------------- V transpose: qkv V-part -> Vt [B,H,64,S] ----------------
__global__ __launch_bounds__(256) void v_transpose(const u16* __restrict__ qkv, u16* __restrict__ Vt) {
  __shared__ u16 tile[256][64];
  const int bh = blockIdx.y;
  const int b = bh >> 4, h = bh & 15;
  const int s0 = blockIdx.x * 256;
  const int tid = threadIdx.x;
  {
    const int c = tid & 7;
    const int r = tid >> 3;
#pragma unroll
    for (int p = 0; p < 8; ++p) {
      int s = r + p * 32;
      const u16* src = qkv + ((size_t)((b << 11) + s0 + s)) * 3072 + 2048 + h * 64 + c * 8;
      *(uint4*)&tile[s][c * 8] = *(const uint4*)src;
    }
  }
  __syncthreads();
  {
    const int c = tid & 31;
    const int r = tid >> 5;
#pragma unroll
    for (int p = 0; p < 8; ++p) {
      int d = r + p * 8;
      u16 tmp[8];
#pragma unroll
      for (int j = 0; j < 8; ++j) tmp[j] = tile[c * 8 + j][d];
      u16* dst = Vt + ((size_t)bh * 64 + d) * 2048 + s0 + c * 8;
      *(uint4*)dst = *(uint4*)tmp;
    }
  }
}

// ---------------- causal flash attention v5 ----------------
// 4 waves/block, 4-way k-split per 32-row q-tile. Register software-pipeline:
// K[t+1]/V[t+1] prefetched into a second reg set while tile t computes.
// Cross-half reduces via permlane32_swap (VALU) instead of ds_permute shfl.
__global__ __launch_bounds__(256, 2) void attn5(const u16* __restrict__ Qr, const u16* __restrict__ Kr,
                                                const u16* __restrict__ Vt, u16* __restrict__ Ao) {
  __shared__ float smM[3][64], smL[3][64];
  __shared__ float smO[3][64][33];
  const int tid = threadIdx.x;
  const int lane = tid & 63;
  const int wid = tid >> 6;
  const int bid = blockIdx.x;            // 2048 = 8 xcd * 4 bh * 64 qt
  const int xcd = bid & 7;
  const int rr = bid >> 3;
  const int bh = xcd * 4 + (rr & 3);     // 4 bh per XCD -> K/V 2MB, L2-fits
  const int qt = 63 - (rr >> 2);         // heavy q-tiles dispatched first
  const int q0 = qt * 32;
  const u16* __restrict__ Qp = Qr + ((size_t)bh << 11) * 64;
  const u16* __restrict__ Kp = Kr + ((size_t)bh << 11) * 64;
  const u16* __restrict__ Vp = Vt + ((size_t)bh << 11) * 64;  // [64][2048]
  const int lq = lane & 31;
  const int hi = lane >> 5;

  short8 qf0 = *(const short8*)(Qp + (size_t)(q0 + lq) * 64 + 0 + hi * 8);
  short8 qf1 = *(const short8*)(Qp + (size_t)(q0 + lq) * 64 + 16 + hi * 8);
  short8 qf2 = *(const short8*)(Qp + (size_t)(q0 + lq) * 64 + 32 + hi * 8);
  short8 qf3 = *(const short8*)(Qp + (size_t)(q0 + lq) * 64 + 48 + hi * 8);

  f32x16 o0, o1;
#pragma unroll
  for (int r = 0; r < 16; ++r) { o0[r] = 0.f; o1[r] = 0.f; }
  float m = -1e30f, lsum = 0.f;

  const int nkt = qt + 1;
  const int base = nkt >> 2, rem = nkt & 3;
  const int cnt = base + (wid < rem ? 1 : 0);
  const int beg = wid * base + (wid < rem ? wid : rem);

  if (cnt > 0) {
    const int kb0 = beg << 5;
    const u16* kp = Kp + (size_t)(kb0 + lq) * 64 + hi * 8;
    const u16* vp = Vp + (size_t)lq * 2048 + kb0 + hi * 8;
    short8 kc0 = *(const short8*)(kp);
    short8 kc1 = *(const short8*)(kp + 16);
    short8 kc2 = *(const short8*)(kp + 32);
    short8 kc3 = *(const short8*)(kp + 48);
    short8 vc0 = *(const short8*)(vp);
    short8 vc1 = *(const short8*)(vp + 16);
    short8 vc2 = *(const short8*)(vp + (size_t)32 * 2048);
    short8 vc3 = *(const short8*)(vp + (size_t)32 * 2048 + 16);

    for (int i = 0; i < cnt; ++i) {
      const int kt = beg + i;
      // prefetch next tile (address clamped -> always safe, no branch)
      const int kbn = (beg + (i + 1 < cnt ? i + 1 : i)) << 5;
      const u16* kpn = Kp + (size_t)(kbn + lq) * 64 + hi * 8;
      const u16* vpn = Vp + (size_t)lq * 2048 + kbn + hi * 8;
      short8 kn0 = *(const short8*)(kpn);
      short8 kn1 = *(const short8*)(kpn + 16);
      short8 kn2 = *(const short8*)(kpn + 32);
      short8 kn3 = *(const short8*)(kpn + 48);
      short8 vn0 = *(const short8*)(vpn);
      short8 vn1 = *(const short8*)(vpn + 16);
      short8 vn2 = *(const short8*)(vpn + (size_t)32 * 2048);
      short8 vn3 = *(const short8*)(vpn + (size_t)32 * 2048 + 16);

      f32x16 sc;
#pragma unroll
      for (int r = 0; r < 16; ++r) sc[r] = 0.f;
      sc = __builtin_amdgcn_mfma_f32_32x32x16_bf16(kc0, qf0, sc, 0, 0, 0);
      sc = __builtin_amdgcn_mfma_f32_32x32x16_bf16(kc1, qf1, sc, 0, 0, 0);
      sc = __builtin_amdgcn_mfma_f32_32x32x16_bf16(kc2, qf2, sc, 0, 0, 0);
      sc = __builtin_amdgcn_mfma_f32_32x32x16_bf16(kc3, qf3, sc, 0, 0, 0);

      if (kt == qt) {  // diagonal tile: causal mask
#pragma unroll
        for (int r = 0; r < 16; ++r) {
          int ko = (r & 3) + 8 * (r >> 2) + 4 * hi;
          sc[r] = (ko <= lq) ? sc[r] : -1e30f;
        }
      }

      // row max via max3 nest, cross-half via permlane (VALU)
      float t0 = fmaxf(fmaxf(sc[0], sc[1]), sc[2]);
      float t1 = fmaxf(fmaxf(sc[3], sc[4]), sc[5]);
      float t2 = fmaxf(fmaxf(sc[6], sc[7]), sc[8]);
      float t3 = fmaxf(fmaxf(sc[9], sc[10]), sc[11]);
      float t4 = fmaxf(fmaxf(sc[12], sc[13]), sc[14]);
      float t5 = fmaxf(fmaxf(t0, t1), sc[15]);
      float t6 = fmaxf(fmaxf(t2, t3), t4);
      float pmax = xhalf_max(fmaxf(t5, t6));

      // defer-max (log2 domain, THR = 8 nats * log2e = 11.5)
      if (!__all(pmax - m <= 11.5f)) {
        float nm = fmaxf(m, pmax);
        float alpha = __builtin_exp2f(m - nm);
        lsum *= alpha;
#pragma unroll
        for (int r = 0; r < 16; ++r) { o0[r] *= alpha; o1[r] *= alpha; }
        m = nm;
      }

      // P = 2^(S - m), in place
#pragma unroll
      for (int r = 0; r < 16; ++r) sc[r] = __builtin_exp2f(sc[r] - m);
      float r8[8];
#pragma unroll
      for (int r = 0; r < 8; ++r) r8[r] = sc[r] + sc[r + 8];
#pragma unroll
      for (int s = 4; s >= 1; s >>= 1)
#pragma unroll
        for (int r = 0; r < s; ++r) r8[r] += r8[r + s];
      lsum += xhalf_sum(r8[0]);

      // P -> bf16 B-operand: cvt_pk pairs + permlane32_swap
      unsigned w[8];
#pragma unroll
      for (int t = 0; t < 8; ++t) {
        unsigned d;
        asm("v_cvt_pk_bf16_f32 %0, %1, %2" : "=v"(d) : "v"(sc[2 * t]), "v"(sc[2 * t + 1]));
        w[t] = d;
      }
      short8 pb0, pb1;
      {
        uint2v r1 = __builtin_amdgcn_permlane32_swap(w[0], w[2], false, false);
        uint2v r2 = __builtin_amdgcn_permlane32_swap(w[1], w[3], false, false);
        unsigned r1x = r1.x, r1y = r1.y, r2x = r2.x, r2y = r2.y;
        uint4v t4v; t4v.x = r1x; t4v.y = r2x; t4v.z = r1y; t4v.w = r2y;
        pb0 = __builtin_bit_cast(short8, t4v);
        uint2v r3 = __builtin_amdgcn_permlane32_swap(w[4], w[6], false, false);
        uint2v r4 = __builtin_amdgcn_permlane32_swap(w[5], w[7], false, false);
        unsigned r3x = r3.x, r3y = r3.y, r4x = r4.x, r4y = r4.y;
        uint4v t5v; t5v.x = r3x; t5v.y = r4x; t5v.z = r3y; t5v.w = r4y;
        pb1 = __builtin_bit_cast(short8, t5v);
      }

      o0 = __builtin_amdgcn_mfma_f32_32x32x16_bf16(vc0, pb0, o0, 0, 0, 0);
      o0 = __builtin_amdgcn_mfma_f32_32x32x16_bf16(vc1, pb1, o0, 0, 0, 0);
      o1 = __builtin_amdgcn_mfma_f32_32x32x16_bf16(vc2, pb0, o1, 0, 0, 0);
      o1 = __builtin_amdgcn_mfma_f32_32x32x16_bf16(vc3, pb1, o1, 0, 0, 0);

      // rotate prefetch -> current
      kc0 = kn0; kc1 = kn1; kc2 = kn2; kc3 = kn3;
      vc0 = vn0; vc1 = vn1; vc2 = vn2; vc3 = vn3;
    }
  }

  // merge the 4 waves' partials (waves 1..3 publish; wave 0 combines)
  if (wid != 0) {
    smM[wid - 1][lane] = m;
    smL[wid - 1][lane] = lsum;
#pragma unroll
    for (int r = 0; r < 16; ++r) smO[wid - 1][lane][r] = o0[r];
#pragma unroll
    for (int r = 0; r < 16; ++r) smO[wid - 1][lane][16 + r] = o1[r];
  }
  __syncthreads();
  if (wid == 0) {
    float m1 = smM[0][lane], m2 = smM[1][lane], m3 = smM[2][lane];
    float M = fmaxf(fmaxf(m, m1), fmaxf(m2, m3));
    float a0 = __builtin_exp2f(m - M);
    float a1 = __builtin_exp2f(m1 - M);
    float a2 = __builtin_exp2f(m2 - M);
    float a3 = __builtin_exp2f(m3 - M);
    float L = lsum * a0 + smL[0][lane] * a1 + smL[1][lane] * a2 + smL[2][lane] * a3;
    float inv = 1.f / L;
    const int b = bh >> 4, h = bh & 15;
    u16* outp = Ao + ((size_t)(b << 11) + q0 + lq) * 1024 + h * 64;
#pragma unroll
    for (int g = 0; g < 4; ++g) {
      int d = 8 * g + 4 * hi;
      float c[8];
#pragma unroll
      for (int j = 0; j < 4; ++j) {
        c[j] = (o0[4 * g + j] * a0 + smO[0][lane][4 * g + j] * a1 +
                smO[1][lane][4 * g + j] * a2 + smO[2][lane][4 * g + j] * a3) * inv;
        c[4 + j] = (o1[4 * g + j] * a0 + smO[0][lane][16 + 4 * g + j] * a1 +
                    smO[1][lane][16 + 4 * g + j] * a2 + smO[2][lane][16 + 4 * g + j] * a3) * inv;
      }
      uint2v w0;
      w0.x = f2bf(c[0]) | ((unsigned)f2bf(c[1]) << 16);
      w0.y = f2bf(c[2]) | ((unsigned)f2bf(c[3]) << 16);
      *(uint2v*)(outp + d) = w0;
      uint2v w1;
      w1.x = f2bf(c[4]) | ((unsigned)f2bf(c[5]) << 16);
      w1.y = f2bf(c[6]) | ((unsigned)f2bf(c[7]) << 16);
      *(uint2v*)(outp + 32 + d) = w1;
    }
  }
}

extern "C" void kernel_launch(void* const* d_in, const int* in_sizes, int n_in,
                              void* d_out, int out_size, void* d_ws, size_t ws_size,
                              hipStream_t stream) {
  const float* x = (const float*)d_in[0];
  const int* pos = (const int*)d_in[1];
  const float* Wqkv = (const float*)d_in[2];
  const float* Wo = (const float*)d_in[3];
  float* out = (float*)d_out;

  char* ws = (char*)d_ws;
  const size_t MB = 1024 * 1024;
  u16* xb     = (u16*)(ws);             //  8 MB: [4096,1024]
  u16* wqkvb  = (u16*)(ws + 8 * MB);    //  6 MB: [3072,1024]
  u16* wob    = (u16*)(ws + 14 * MB);   //  2 MB: [1024,1024]
  u16* qkv    = (u16*)(ws + 16 * MB);   // 24 MB: [4096,3072]
  u16* Qr     = (u16*)(ws + 40 * MB);   //  8 MB: [B,H,S,64] (pre-scaled 0.125*log2e)
  u16* Kr     = (u16*)(ws + 48 * MB);   //  8 MB
  u16* Vt     = (u16*)(ws + 56 * MB);   //  8 MB: [B,H,64,S]
  u16* ao     = (u16*)(ws + 64 * MB);   //  8 MB: [4096,1024]

  cvt_all<<<8192, 256, 0, stream>>>(x, Wqkv, Wo, xb, wqkvb, wob);
  gemm_bt<u16><<<dim3(32, 24), 256, 0, stream>>>(xb, wqkvb, qkv, 4096, 3072, 1024);
  rope_qk<<<8192, 256, 0, stream>>>(qkv, pos, Qr, Kr);
  v_transpose<<<dim3(8, 32), 256, 0, stream>>>(qkv, Vt);
  attn5<<<2048, 256, 0, stream>>>(Qr, Kr, Vt, ao);
  gemm_bt64<float><<<dim3(64, 8), 256, 0, stream>>>(ao, wob, out, 4096, 1024, 1024);
}

// Round 7
// 194.674 us; speedup vs baseline: 1.1998x; 1.1709x over previous
//
#include <hip/hip_runtime.h>
#include <hip/hip_bf16.h>

// Problem constants: B=2, S=2048, H=16, dk=64, D_MODEL=1024, THETA=10000
// Packed fragment layouts (this round's change):
//   Qf/Kf[bh][t][j][lane][e]  = X[bh][t*32 + (lane&31)][j*16 + (lane>>5)*8 + e]
//   Vf[bh][t][seg][lane][e]   = V[bh][t*32 + (seg&1)*16 + (lane>>5)*8 + e][(seg>>1)*32 + (lane&31)]
// so every MFMA fragment load in attn is base + lane*16B (fully coalesced).

using u16 = unsigned short;
typedef __attribute__((ext_vector_type(8))) short short8;
typedef __attribute__((ext_vector_type(4))) float f32x4;
typedef __attribute__((ext_vector_type(16))) float f32x16;
typedef __attribute__((ext_vector_type(2))) unsigned uint2v;
typedef __attribute__((ext_vector_type(4))) unsigned uint4v;

__device__ __forceinline__ float bf2f(u16 v) {
  unsigned u = ((unsigned)v) << 16; float f; __builtin_memcpy(&f, &u, 4); return f;
}
__device__ __forceinline__ u16 f2bf(float f) {
  unsigned u; __builtin_memcpy(&u, &f, 4);
  return (u16)((u + 0x7fffu + ((u >> 16) & 1u)) >> 16);
}
__device__ __forceinline__ float u2f(unsigned u) {
  float f; __builtin_memcpy(&f, &u, 4); return f;
}
__device__ __forceinline__ unsigned f2u(float f) {
  unsigned u; __builtin_memcpy(&u, &f, 4); return u;
}
__device__ __forceinline__ float xhalf_max(float x) {
  uint2v s = __builtin_amdgcn_permlane32_swap(f2u(x), f2u(x), false, false);
  unsigned ax = s.x, bx = s.y;
  return fmaxf(u2f(ax), u2f(bx));
}
__device__ __forceinline__ float xhalf_sum(float x) {
  uint2v s = __builtin_amdgcn_permlane32_swap(f2u(x), f2u(x), false, false);
  unsigned ax = s.x, bx = s.y;
  return u2f(ax) + u2f(bx);
}

__device__ __forceinline__ void gload_lds16(const void* g, void* l) {
  __builtin_amdgcn_global_load_lds((const __attribute__((address_space(1))) unsigned*)g,
                                   (__attribute__((address_space(3))) unsigned*)l, 16, 0, 0);
}

// ---------------- fused fp32 -> bf16 convert for x, W_qkv, W_o ----------------
__global__ __launch_bounds__(256) void cvt_all(const float* __restrict__ x, const float* __restrict__ wqkv,
                                               const float* __restrict__ wo, u16* __restrict__ xb,
                                               u16* __restrict__ wqkvb, u16* __restrict__ wob) {
  int i = blockIdx.x * 256 + threadIdx.x;  // 2M quads total
  const float* src; u16* dst; int off;
  if (i < 1048576) { src = x; dst = xb; off = i; }
  else if (i < 1048576 + 786432) { src = wqkv; dst = wqkvb; off = i - 1048576; }
  else { src = wo; dst = wob; off = i - (1048576 + 786432); }
  float4 v = *(const float4*)(src + (size_t)off * 4);
  unsigned lo = f2bf(v.x) | ((unsigned)f2bf(v.y) << 16);
  unsigned hi = f2bf(v.z) | ((unsigned)f2bf(v.w) << 16);
  uint2 w; w.x = lo; w.y = hi;
  *(uint2*)(dst + (size_t)off * 4) = w;
}

// ---------------- GEMM 128x128: C[M,N] = A[M,K] * B[N,K]^T ----------------
template <typename OutT>
__global__ __launch_bounds__(256) void gemm_bt(const u16* __restrict__ A, const u16* __restrict__ B,
                                               OutT* __restrict__ C, int M, int N, int K) {
  __shared__ u16 As[128 * 32];
  __shared__ u16 Bs[128 * 32];
  const int tid = threadIdx.x;
  const int wave = tid >> 6;
  const int lane = tid & 63;
  const int m0 = blockIdx.x * 128;
  const int n0 = blockIdx.y * 128;
  const int wm = (wave >> 1) * 64;
  const int wn = (wave & 1) * 64;

  f32x4 acc[4][4];
#pragma unroll
  for (int m = 0; m < 4; ++m)
#pragma unroll
    for (int n = 0; n < 4; ++n) acc[m][n] = (f32x4){0.f, 0.f, 0.f, 0.f};

  const int srow = lane >> 2;
  const int scol = (lane & 3) * 8;
  const u16* Ag0 = A + (size_t)(m0 + wave * 16 + srow) * K + scol;
  const u16* Ag1 = A + (size_t)(m0 + 64 + wave * 16 + srow) * K + scol;
  const u16* Bg0 = B + (size_t)(n0 + wave * 16 + srow) * K + scol;
  const u16* Bg1 = B + (size_t)(n0 + 64 + wave * 16 + srow) * K + scol;
  u16* AsW0 = As + (wave * 16) * 32;
  u16* AsW1 = As + (64 + wave * 16) * 32;
  u16* BsW0 = Bs + (wave * 16) * 32;
  u16* BsW1 = Bs + (64 + wave * 16) * 32;

  const int fr = lane & 15;
  const int fk = (lane >> 4) * 8;

  for (int k0 = 0; k0 < K; k0 += 32) {
    __syncthreads();
    gload_lds16(Ag0 + k0, AsW0);
    gload_lds16(Ag1 + k0, AsW1);
    gload_lds16(Bg0 + k0, BsW0);
    gload_lds16(Bg1 + k0, BsW1);
    __syncthreads();

    short8 af[4], bf[4];
#pragma unroll
    for (int m = 0; m < 4; ++m)
      af[m] = *(const short8*)(As + (wm + m * 16 + fr) * 32 + fk);
#pragma unroll
    for (int n = 0; n < 4; ++n)
      bf[n] = *(const short8*)(Bs + (wn + n * 16 + fr) * 32 + fk);
#pragma unroll
    for (int m = 0; m < 4; ++m)
#pragma unroll
      for (int n = 0; n < 4; ++n)
        acc[m][n] = __builtin_amdgcn_mfma_f32_16x16x32_bf16(af[m], bf[n], acc[m][n], 0, 0, 0);
  }

  const int fg = lane >> 4;
#pragma unroll
  for (int m = 0; m < 4; ++m)
#pragma unroll
    for (int n = 0; n < 4; ++n)
#pragma unroll
      for (int r = 0; r < 4; ++r) {
        int row = m0 + wm + m * 16 + fg * 4 + r;
        int col = n0 + wn + n * 16 + fr;
        if constexpr (sizeof(OutT) == 2)
          C[(size_t)row * N + col] = (OutT)f2bf(acc[m][n][r]);
        else
          C[(size_t)row * N + col] = (OutT)acc[m][n][r];
      }
}

// ---------------- GEMM 64x128 (occupancy variant for small-M outputs) ----------------
template <typename OutT>
__global__ __launch_bounds__(256) void gemm_bt64(const u16* __restrict__ A, const u16* __restrict__ B,
                                                 OutT* __restrict__ C, int M, int N, int K) {
  __shared__ u16 As[64 * 32];   // 4 KB
  __shared__ u16 Bs[128 * 32];  // 8 KB
  const int tid = threadIdx.x;
  const int wave = tid >> 6;
  const int lane = tid & 63;
  const int m0 = blockIdx.x * 64;
  const int n0 = blockIdx.y * 128;
  const int wm = (wave >> 1) * 32;
  const int wn = (wave & 1) * 64;

  f32x4 acc[2][4];
#pragma unroll
  for (int m = 0; m < 2; ++m)
#pragma unroll
    for (int n = 0; n < 4; ++n) acc[m][n] = (f32x4){0.f, 0.f, 0.f, 0.f};

  const int srow = lane >> 2;
  const int scol = (lane & 3) * 8;
  const u16* Ag = A + (size_t)(m0 + wave * 16 + srow) * K + scol;
  const u16* Bg0 = B + (size_t)(n0 + wave * 16 + srow) * K + scol;
  const u16* Bg1 = B + (size_t)(n0 + 64 + wave * 16 + srow) * K + scol;
  u16* AsW = As + (wave * 16) * 32;
  u16* BsW0 = Bs + (wave * 16) * 32;
  u16* BsW1 = Bs + (64 + wave * 16) * 32;

  const int fr = lane & 15;
  const int fk = (lane >> 4) * 8;

  for (int k0 = 0; k0 < K; k0 += 32) {
    __syncthreads();
    gload_lds16(Ag + k0, AsW);
    gload_lds16(Bg0 + k0, BsW0);
    gload_lds16(Bg1 + k0, BsW1);
    __syncthreads();

    short8 af[2], bf[4];
#pragma unroll
    for (int m = 0; m < 2; ++m)
      af[m] = *(const short8*)(As + (wm + m * 16 + fr) * 32 + fk);
#pragma unroll
    for (int n = 0; n < 4; ++n)
      bf[n] = *(const short8*)(Bs + (wn + n * 16 + fr) * 32 + fk);
#pragma unroll
    for (int m = 0; m < 2; ++m)
#pragma unroll
      for (int n = 0; n < 4; ++n)
        acc[m][n] = __builtin_amdgcn_mfma_f32_16x16x32_bf16(af[m], bf[n], acc[m][n], 0, 0, 0);
  }

  const int fg = lane >> 4;
#pragma unroll
  for (int m = 0; m < 2; ++m)
#pragma unroll
    for (int n = 0; n < 4; ++n)
#pragma unroll
      for (int r = 0; r < 4; ++r) {
        int row = m0 + wm + m * 16 + fg * 4 + r;
        int col = n0 + wn + n * 16 + fr;
        if constexpr (sizeof(OutT) == 2)
          C[(size_t)row * N + col] = (OutT)f2bf(acc[m][n][r]);
        else
          C[(size_t)row * N + col] = (OutT)acc[m][n][r];
      }
}

// ---------------- RoPE: qkv -> Qf,Kf packed fragment layout; Q pre-scaled 0.125*log2(e) ----------------
__global__ __launch_bounds__(256) void rope_qk(const u16* __restrict__ qkv, const int* __restrict__ pos,
                                               u16* __restrict__ Qf, u16* __restrict__ Kf) {
  int t = blockIdx.x * 256 + threadIdx.x;
  int i = t & 31;          // d0 = 2i
  int h = (t >> 5) & 15;
  int s = (t >> 9) & 2047;
  int b = t >> 20;
  float p = (float)pos[(b << 11) + s];
  float ang = p * __builtin_exp2f(-(float)i * 0.41524101186f);
  float sn, cs;
  sincosf(ang, &sn, &cs);
  const u16* base = qkv + ((size_t)((b << 11) + s)) * 3072 + h * 64 + 2 * i;
  float qe = bf2f(base[0]), qo = bf2f(base[1]);
  float ke = bf2f(base[1024]), ko = bf2f(base[1025]);
  const float QS = 0.18033688011112043f;  // 0.125 * log2(e)
  unsigned qw = f2bf((cs * qe - sn * qo) * QS) | ((unsigned)f2bf((sn * qe + cs * qo) * QS) << 16);
  unsigned kw = f2bf(cs * ke - sn * ko) | ((unsigned)f2bf(sn * ke + cs * ko) << 16);
  // packed fragment address
  int bh = (b << 4) + h;
  int d0 = 2 * i;
  int tile = s >> 5;
  int l = (s & 31) + 32 * ((d0 >> 3) & 1);
  int j = d0 >> 4;
  int e = d0 & 7;
  size_t o = ((((size_t)bh * 64 + tile) * 4 + j) * 64 + l) * 8 + e;
  *(unsigned*)(Qf + o) = qw;
  *(unsigned*)(Kf + o) = kw;
}

// ---------------- V pack: qkv V-part -> Vf packed fragment layout ----------------
__global__ __launch_bounds__(256) void v_pack(const u16* __restrict__ qkv, u16* __restrict__ Vf) {
  __shared__ u16 lds[64][72];  // [s_local][d], padded
  const int bh = blockIdx.y;
  const int b = bh >> 4, h = bh & 15;
  const int s0 = blockIdx.x * 64;  // two 32-row k-tiles per block
  const int t = threadIdx.x;
  {
    const int r = t >> 3;      // 0..31
    const int c = t & 7;       // 16B chunk of the 128B d-row
#pragma unroll
    for (int p = 0; p < 2; ++p) {
      int s = r + p * 32;
      const u16* src = qkv + ((size_t)((b << 11) + s0 + s)) * 3072 + 2048 + h * 64 + c * 8;
      *(uint4*)&lds[s][c * 8] = *(const uint4*)src;
    }
  }
  __syncthreads();
#pragma unroll
  for (int p = 0; p < 2; ++p) {
    int item = t + p * 256;          // 512 items: [tt][seg][l]
    int tt = item >> 8;
    int seg = (item >> 6) & 3;
    int l = item & 63;
    int d = (seg >> 1) * 32 + (l & 31);
    int sb = tt * 32 + (seg & 1) * 16 + (l >> 5) * 8;
    u16 tmp[8];
#pragma unroll
    for (int e = 0; e < 8; ++e) tmp[e] = lds[sb + e][d];
    int kt = (s0 >> 5) + tt;
    size_t o = ((((size_t)bh * 64 + kt) * 4 + seg) * 64 + l) * 8;
    *(uint4*)(Vf + o) = *(uint4*)tmp;
  }
}

// ---------------- causal flash attention v6: packed-fragment coalesced loads ----------------
// 4 waves/block, 4-way k-split per 32-row q-tile, register prefetch pipeline.
// All K/V/Q fragment loads are base + lane*16B (one 1KB coalesced transaction).
__global__ __launch_bounds__(256, 2) void attn6(const u16* __restrict__ Qf, const u16* __restrict__ Kf,
                                                const u16* __restrict__ Vf, u16* __restrict__ Ao) {
  __shared__ float smM[3][64], smL[3][64];
  __shared__ float smO[3][64][33];
  const int tid = threadIdx.x;
  const int lane = tid & 63;
  const int wid = tid >> 6;
  const int bid = blockIdx.x;            // 2048 = 8 xcd * 4 bh * 64 qt
  const int xcd = bid & 7;
  const int rr = bid >> 3;
  const int bh = xcd * 4 + (rr & 3);     // 4 bh per XCD -> K/V 2MB, L2-fits
  const int qt = 63 - (rr >> 2);         // heavy q-tiles dispatched first
  const int q0 = qt * 32;
  const u16* __restrict__ Qp = Qf + (size_t)bh * 131072;  // 64 tiles * 2048
  const u16* __restrict__ Kp = Kf + (size_t)bh * 131072;
  const u16* __restrict__ Vp = Vf + (size_t)bh * 131072;
  const int lq = lane & 31;
  const int hi = lane >> 5;

  const u16* qb = Qp + (size_t)qt * 2048 + lane * 8;
  short8 qf0 = *(const short8*)(qb);
  short8 qf1 = *(const short8*)(qb + 512);
  short8 qf2 = *(const short8*)(qb + 1024);
  short8 qf3 = *(const short8*)(qb + 1536);

  f32x16 o0, o1;
#pragma unroll
  for (int r = 0; r < 16; ++r) { o0[r] = 0.f; o1[r] = 0.f; }
  float m = -1e30f, lsum = 0.f;

  const int nkt = qt + 1;
  const int base = nkt >> 2, rem = nkt & 3;
  const int cnt = base + (wid < rem ? 1 : 0);
  const int beg = wid * base + (wid < rem ? wid : rem);

  if (cnt > 0) {
    const u16* kp = Kp + (size_t)beg * 2048 + lane * 8;
    const u16* vp = Vp + (size_t)beg * 2048 + lane * 8;
    short8 kc0 = *(const short8*)(kp);
    short8 kc1 = *(const short8*)(kp + 512);
    short8 kc2 = *(const short8*)(kp + 1024);
    short8 kc3 = *(const short8*)(kp + 1536);
    short8 vc0 = *(const short8*)(vp);
    short8 vc1 = *(const short8*)(vp + 512);
    short8 vc2 = *(const short8*)(vp + 1024);
    short8 vc3 = *(const short8*)(vp + 1536);

    for (int i = 0; i < cnt; ++i) {
      const int kt = beg + i;
      // prefetch next tile (clamped -> safe, no branch)
      const int ktn = beg + (i + 1 < cnt ? i + 1 : i);
      const u16* kpn = Kp + (size_t)ktn * 2048 + lane * 8;
      const u16* vpn = Vp + (size_t)ktn * 2048 + lane * 8;
      short8 kn0 = *(const short8*)(kpn);
      short8 kn1 = *(const short8*)(kpn + 512);
      short8 kn2 = *(const short8*)(kpn + 1024);
      short8 kn3 = *(const short8*)(kpn + 1536);
      short8 vn0 = *(const short8*)(vpn);
      short8 vn1 = *(const short8*)(vpn + 512);
      short8 vn2 = *(const short8*)(vpn + 1024);
      short8 vn3 = *(const short8*)(vpn + 1536);

      f32x16 sc;
#pragma unroll
      for (int r = 0; r < 16; ++r) sc[r] = 0.f;
      sc = __builtin_amdgcn_mfma_f32_32x32x16_bf16(kc0, qf0, sc, 0, 0, 0);
      sc = __builtin_amdgcn_mfma_f32_32x32x16_bf16(kc1, qf1, sc, 0, 0, 0);
      sc = __builtin_amdgcn_mfma_f32_32x32x16_bf16(kc2, qf2, sc, 0, 0, 0);
      sc = __builtin_amdgcn_mfma_f32_32x32x16_bf16(kc3, qf3, sc, 0, 0, 0);

      if (kt == qt) {  // diagonal tile: causal mask
#pragma unroll
        for (int r = 0; r < 16; ++r) {
          int ko = (r & 3) + 8 * (r >> 2) + 4 * hi;
          sc[r] = (ko <= lq) ? sc[r] : -1e30f;
        }
      }

      // row max via max3 nest, cross-half via permlane (VALU)
      float t0 = fmaxf(fmaxf(sc[0], sc[1]), sc[2]);
      float t1 = fmaxf(fmaxf(sc[3], sc[4]), sc[5]);
      float t2 = fmaxf(fmaxf(sc[6], sc[7]), sc[8]);
      float t3 = fmaxf(fmaxf(sc[9], sc[10]), sc[11]);
      float t4 = fmaxf(fmaxf(sc[12], sc[13]), sc[14]);
      float t5 = fmaxf(fmaxf(t0, t1), sc[15]);
      float t6 = fmaxf(fmaxf(t2, t3), t4);
      float pmax = xhalf_max(fmaxf(t5, t6));

      // defer-max (log2 domain, THR = 8 nats * log2e = 11.5)
      if (!__all(pmax - m <= 11.5f)) {
        float nm = fmaxf(m, pmax);
        float alpha = __builtin_exp2f(m - nm);
        lsum *= alpha;
#pragma unroll
        for (int r = 0; r < 16; ++r) { o0[r] *= alpha; o1[r] *= alpha; }
        m = nm;
      }

      // P = 2^(S - m), in place
#pragma unroll
      for (int r = 0; r < 16; ++r) sc[r] = __builtin_exp2f(sc[r] - m);
      float r8[8];
#pragma unroll
      for (int r = 0; r < 8; ++r) r8[r] = sc[r] + sc[r + 8];
#pragma unroll
      for (int s = 4; s >= 1; s >>= 1)
#pragma unroll
        for (int r = 0; r < s; ++r) r8[r] += r8[r + s];
      lsum += xhalf_sum(r8[0]);

      // P -> bf16 B-operand: cvt_pk pairs + permlane32_swap
      unsigned w[8];
#pragma unroll
      for (int t = 0; t < 8; ++t) {
        unsigned d;
        asm("v_cvt_pk_bf16_f32 %0, %1, %2" : "=v"(d) : "v"(sc[2 * t]), "v"(sc[2 * t + 1]));
        w[t] = d;
      }
      short8 pb0, pb1;
      {
        uint2v r1 = __builtin_amdgcn_permlane32_swap(w[0], w[2], false, false);
        uint2v r2 = __builtin_amdgcn_permlane32_swap(w[1], w[3], false, false);
        unsigned r1x = r1.x, r1y = r1.y, r2x = r2.x, r2y = r2.y;
        uint4v t4v; t4v.x = r1x; t4v.y = r2x; t4v.z = r1y; t4v.w = r2y;
        pb0 = __builtin_bit_cast(short8, t4v);
        uint2v r3 = __builtin_amdgcn_permlane32_swap(w[4], w[6], false, false);
        uint2v r4 = __builtin_amdgcn_permlane32_swap(w[5], w[7], false, false);
        unsigned r3x = r3.x, r3y = r3.y, r4x = r4.x, r4y = r4.y;
        uint4v t5v; t5v.x = r3x; t5v.y = r4x; t5v.z = r3y; t5v.w = r4y;
        pb1 = __builtin_bit_cast(short8, t5v);
      }

      o0 = __builtin_amdgcn_mfma_f32_32x32x16_bf16(vc0, pb0, o0, 0, 0, 0);
      o0 = __builtin_amdgcn_mfma_f32_32x32x16_bf16(vc1, pb1, o0, 0, 0, 0);
      o1 = __builtin_amdgcn_mfma_f32_32x32x16_bf16(vc2, pb0, o1, 0, 0, 0);
      o1 = __builtin_amdgcn_mfma_f32_32x32x16_bf16(vc3, pb1, o1, 0, 0, 0);

      // rotate prefetch -> current
      kc0 = kn0; kc1 = kn1; kc2 = kn2; kc3 = kn3;
      vc0 = vn0; vc1 = vn1; vc2 = vn2; vc3 = vn3;
    }
  }

  // merge the 4 waves' partials (waves 1..3 publish; wave 0 combines)
  if (wid != 0) {
    smM[wid - 1][lane] = m;
    smL[wid - 1][lane] = lsum;
#pragma unroll
    for (int r = 0; r < 16; ++r) smO[wid - 1][lane][r] = o0[r];
#pragma unroll
    for (int r = 0; r < 16; ++r) smO[wid - 1][lane][16 + r] = o1[r];
  }
  __syncthreads();
  if (wid == 0) {
    float m1 = smM[0][lane], m2 = smM[1][lane], m3 = smM[2][lane];
    float M = fmaxf(fmaxf(m, m1), fmaxf(m2, m3));
    float a0 = __builtin_exp2f(m - M);
    float a1 = __builtin_exp2f(m1 - M);
    float a2 = __builtin_exp2f(m2 - M);
    float a3 = __builtin_exp2f(m3 - M);
    float L = lsum * a0 + smL[0][lane] * a1 + smL[1][lane] * a2 + smL[2][lane] * a3;
    float inv = 1.f / L;
    const int b = bh >> 4, h = bh & 15;
    u16* outp = Ao + ((size_t)(b << 11) + q0 + lq) * 1024 + h * 64;
#pragma unroll
    for (int g = 0; g < 4; ++g) {
      int d = 8 * g + 4 * hi;
      float c[8];
#pragma unroll
      for (int j = 0; j < 4; ++j) {
        c[j] = (o0[4 * g + j] * a0 + smO[0][lane][4 * g + j] * a1 +
                smO[1][lane][4 * g + j] * a2 + smO[2][lane][4 * g + j] * a3) * inv;
        c[4 + j] = (o1[4 * g + j] * a0 + smO[0][lane][16 + 4 * g + j] * a1 +
                    smO[1][lane][16 + 4 * g + j] * a2 + smO[2][lane][16 + 4 * g + j] * a3) * inv;
      }
      uint2v w0;
      w0.x = f2bf(c[0]) | ((unsigned)f2bf(c[1]) << 16);
      w0.y = f2bf(c[2]) | ((unsigned)f2bf(c[3]) << 16);
      *(uint2v*)(outp + d) = w0;
      uint2v w1;
      w1.x = f2bf(c[4]) | ((unsigned)f2bf(c[5]) << 16);
      w1.y = f2bf(c[6]) | ((unsigned)f2bf(c[7]) << 16);
      *(uint2v*)(outp + 32 + d) = w1;
    }
  }
}

extern "C" void kernel_launch(void* const* d_in, const int* in_sizes, int n_in,
                              void* d_out, int out_size, void* d_ws, size_t ws_size,
                              hipStream_t stream) {
  const float* x = (const float*)d_in[0];
  const int* pos = (const int*)d_in[1];
  const float* Wqkv = (const float*)d_in[2];
  const float* Wo = (const float*)d_in[3];
  float* out = (float*)d_out;

  char* ws = (char*)d_ws;
  const size_t MB = 1024 * 1024;
  u16* xb     = (u16*)(ws);             //  8 MB: [4096,1024]
  u16* wqkvb  = (u16*)(ws + 8 * MB);    //  6 MB: [3072,1024]
  u16* wob    = (u16*)(ws + 14 * MB);   //  2 MB: [1024,1024]
  u16* qkv    = (u16*)(ws + 16 * MB);   // 24 MB: [4096,3072]
  u16* Qf     = (u16*)(ws + 40 * MB);   //  8 MB packed fragments (pre-scaled 0.125*log2e)
  u16* Kf     = (u16*)(ws + 48 * MB);   //  8 MB packed fragments
  u16* Vf     = (u16*)(ws + 56 * MB);   //  8 MB packed fragments
  u16* ao     = (u16*)(ws + 64 * MB);   //  8 MB: [4096,1024]

  cvt_all<<<8192, 256, 0, stream>>>(x, Wqkv, Wo, xb, wqkvb, wob);
  gemm_bt<u16><<<dim3(32, 24), 256, 0, stream>>>(xb, wqkvb, qkv, 4096, 3072, 1024);
  rope_qk<<<8192, 256, 0, stream>>>(qkv, pos, Qf, Kf);
  v_pack<<<dim3(32, 32), 256, 0, stream>>>(qkv, Vf);
  attn6<<<2048, 256, 0, stream>>>(Qf, Kf, Vf, ao);
  gemm_bt64<float><<<dim3(64, 8), 256, 0, stream>>>(ao, wob, out, 4096, 1024, 1024);
}